// Round 12
// baseline (386.226 us; speedup 1.0000x reference)
//
#include <hip/hip_runtime.h>
#include <hip/hip_bf16.h>
#include <cstdint>
#include <cstddef>

typedef unsigned short u16;
typedef unsigned int u32;

#define DEV __device__ __forceinline__

DEV float bf2f(u16 u){ union{unsigned int i; float f;} c; c.i = ((unsigned)u)<<16; return c.f; }
DEV u16 f2bf(float f){ union{float f;unsigned int i;} c; c.f=f; unsigned int r = c.i + 0x7FFFu + ((c.i>>16)&1u); return (u16)(r>>16); }
DEV unsigned int pk2(float a, float b){
  __hip_bfloat162 t = __float22bfloat162_rn(float2{a,b});   // v_cvt_pk_bf16_f32
  union { __hip_bfloat162 h; unsigned int u; } cv; cv.h = t; return cv.u;
}
// async global->LDS DMA, 16B per lane; LDS dest must be wave-uniform base + lane*16
DEV void gl_lds16(const void* g, void* l){
  __builtin_amdgcn_global_load_lds(
    (const __attribute__((address_space(1))) unsigned int*)g,
    (__attribute__((address_space(3))) unsigned int*)(uintptr_t)l,
    16, 0, 0);
}

typedef __attribute__((ext_vector_type(8))) short bf16x8;
typedef __attribute__((ext_vector_type(4))) float f32x4;
typedef __attribute__((ext_vector_type(8))) unsigned short us8v;

// ---------------- workspace layout (bytes, all 16B aligned) ----------------
static constexpr size_t OFF_XW    = 0;                                   // [128][16] f32
static constexpr size_t OFF_WHX2  = 8192;                                // [128][1600] f32
static constexpr size_t OFF_WHX3  = OFF_WHX2 + (size_t)128*1600*4;       // [128][1200] f32
static constexpr size_t OFF_W21   = OFF_WHX3 + (size_t)128*1200*4;       // conv1 w [ci][k][co] f32
static constexpr size_t OFF_WB2   = OFF_W21  + (size_t)288*4;            // conv2 w bf16
static constexpr size_t OFF_WB3   = OFF_WB2  + (size_t)18432*2;
static constexpr size_t OFF_WB4   = OFF_WB3  + (size_t)36864*2;
static constexpr size_t OFF_WB5   = OFF_WB4  + (size_t)36864*2;
static constexpr size_t OFF_W26   = OFF_WB5  + (size_t)18432*2;          // conv6 w f32 [ci][k]
static constexpr size_t OFF_PAR   = OFF_W26  + (size_t)288*4;            // 6 x 768B
static constexpr size_t OFF_WPACK = OFF_PAR  + (size_t)6*768;            // score B-frags bf16
static constexpr size_t OFF_WB1G  = OFF_WPACK+ (size_t)20480*2;          // gemm1 W [1216][608] bf16
static constexpr size_t OFF_RBWB  = OFF_WB1G + (size_t)1216*608*2;       // gemm2 W [1600][1216] bf16
static constexpr size_t OFF_RPWB  = OFF_RBWB + (size_t)1600*1216*2;      // gemm3 W [1216][1600] bf16
static constexpr size_t OFF_CAT   = OFF_RPWB + (size_t)1216*1600*2;      // [128][608] bf16 (concat ht,x)
static constexpr size_t OFF_WHX1B = OFF_CAT  + (size_t)128*608*2;        // [128][1216] bf16
static constexpr size_t OFF_O16B  = OFF_WHX1B+ (size_t)128*1216*2;       // [128][1600] bf16
static constexpr size_t OFF_CT    = OFF_O16B + (size_t)128*1600*2;       // [128][300] f32
static constexpr size_t OFF_A32   = OFF_CT   + (size_t)128*300*4;        // [128][1764][32] bf16
static constexpr size_t OFF_B64   = OFF_A32  + (size_t)128*1764*32*2;    // [128][1764][64] bf16
static constexpr size_t OFF_C64   = OFF_B64  + (size_t)128*1764*64*2;    // [128][1764][64] bf16
static constexpr size_t OFF_P0    = OFF_C64  + (size_t)128*1764*64*2;    // [128][1764] bf16
static constexpr size_t OFF_Y6    = OFF_P0   + (size_t)128*1764*2;       // [128][1764] bf16
static constexpr size_t OFF_PART  = OFF_C64;  // attn partials alias C64 (dead before conv3 writes)
// PART [128][64][608] f32 = 19.9 MB < C64 (28.9 MB)

// ---------------- zero rings of P0/Y6 + cat pad ----------------
DEV void ring0(u16* buf, int j){
  int b = j/164, i = j%164;
  int y, x;
  if      (i < 42){ y = 0;        x = i; }
  else if (i < 84){ y = 41;       x = i-42; }
  else if (i < 124){ y = i-84+1;  x = 0; }
  else             { y = i-124+1; x = 41; }
  buf[(size_t)b*1764 + y*42 + x] = 0;
}
__global__ __launch_bounds__(256) void zero_mega(u16* __restrict__ p0, u16* __restrict__ y6,
                                                 u16* __restrict__ catb){
  int id = blockIdx.x*256 + threadIdx.x;
  if (id < 20992) ring0(p0, id);
  else if (id < 41984) ring0(y6, id-20992);
  else if (id < 42112){
    int b = id - 41984;
    us8v z = {0,0,0,0,0,0,0,0};
    *(us8v*)(catb + (size_t)b*608 + 600) = z;
  }
}

// ---------------- mega repack: all weights + BN pars ----------------
struct RArgs {
  const float* cw[6]; const float* cb[6]; const float* cg[6]; const float* cbe[6];
  const float* Wh; const float* Wht; const float* Wg; const float* rbw; const float* rpw;
  float* w21; float* w26; float* par;
  u16 *wb2, *wb3, *wb4, *wb5, *wpack, *Wb1, *rbwb, *rpwb;
};
DEV void cvW(const float* w, u16* dst, size_t j, int CI){
  int ci = j % CI; size_t rem = j / CI; int dydx = rem % 9; int co = rem / 9;
  dst[j] = f2bf(w[((size_t)co*CI + ci)*9 + dydx]);
}
__global__ __launch_bounds__(256) void mega_repack(RArgs a){
  const float isc = 1.0f/sqrtf(1.00001f);
  for (size_t id = (size_t)blockIdx.x*256 + threadIdx.x; id < 4762947ull;
       id += (size_t)gridDim.x*256){
    if (id < 288){
      int co = id % 32; size_t rem = id / 32; int k = rem % 9;
      a.w21[id] = a.cw[0][co*9 + k];
    } else if (id < 18720){ cvW(a.cw[1], a.wb2, id-288, 32); }
    else if (id < 55584){ cvW(a.cw[2], a.wb3, id-18720, 64); }
    else if (id < 92448){ cvW(a.cw[3], a.wb4, id-55584, 64); }
    else if (id < 110880){ cvW(a.cw[4], a.wb5, id-92448, 64); }
    else if (id < 111168){
      size_t j = id - 110880;              // w26 identity [ci*9+k]
      a.w26[j] = a.cw[5][j];
    } else if (id < 131648){
      size_t j = id - 111168;              // wpack (zero for k>=300 -> kills garbage products)
      int jj = j&7, col=(int)((j>>3)&15), kg=(int)((j>>7)&3); size_t rest=j>>9;
      int ks = (int)(rest%10), tz = (int)(rest/10);
      int k = ks*32 + kg*8 + jj;
      const float* src = tz ? a.Wht : a.Wh;
      a.wpack[j] = f2bf((col<10 && k<300)? src[col*300+k] : 0.f);
    } else if (id < 870976){
      size_t j = id - 131648; int k = (int)(j % 608); int n = (int)(j / 608);
      a.Wb1[j] = f2bf((n<1200 && k<600)? a.Wg[(size_t)n*600+k] : 0.f);
    } else if (id < 2816576){
      size_t j = id - 870976; int k = (int)(j % 1216); int n = (int)(j / 1216);
      a.rbwb[j] = f2bf((k<1200)? a.rbw[(size_t)n*1200+k] : 0.f);
    } else if (id < 4762176){
      size_t j = id - 2816576; int k = (int)(j % 1600); int n = (int)(j / 1600);
      a.rpwb[j] = f2bf((n<1200)? a.rpw[(size_t)n*1600+k] : 0.f);
    } else {
      size_t j = id - 4762176;             // 771 par entries
      int ci, CO; size_t base;
      if (j < 96){ ci=0; CO=32; base=0; }
      else if (j < 288){ ci=1; CO=64; base=96; }
      else if (j < 480){ ci=2; CO=64; base=288; }
      else if (j < 672){ ci=3; CO=64; base=480; }
      else if (j < 768){ ci=4; CO=32; base=672; }
      else { ci=5; CO=1; base=768; }
      size_t jj = j - base; int t = (int)(jj / CO); int c = (int)(jj % CO);
      float* p = a.par + (size_t)ci*192;
      p[t*CO + c] = (t==0)? a.cb[ci][c] : (t==1)? a.cg[ci][c]*isc : a.cbe[ci][c];
    }
  }
}

// ---------------- xW[b][k] = sum_d x[b,d]*Wx[k,d] ----------------
__global__ __launch_bounds__(64) void xw_k(const float* __restrict__ x, const float* __restrict__ Wx,
                                           float* __restrict__ xw){
  int id = blockIdx.x;           // 128*10
  int b = id/10, k = id%10;
  int lane = threadIdx.x;
  float a = 0.f;
  for (int d = lane; d < 300; d += 64)
    a = fmaf(x[b*300+d], Wx[k*300+d], a);
  #pragma unroll
  for (int off=1; off<64; off<<=1) a += __shfl_xor(a, off);
  if (lane==0) xw[b*16+k] = a;
}

// ---------------- fused attention: async global_load_lds staging (no VGPR round-trip) ----------------
// 16-row chunk; 3 tensors staged f32 linear (stride 300 = global order, DMA-compatible).
// All 15 DMA requests/thread in flight; one barrier drains. MFMA converts f32->bf16 at use;
// K-slices 300..319 read neighbor garbage but wpack is zero there.
__global__ __launch_bounds__(256) void attn_fused(const float* __restrict__ hs, const float* __restrict__ pht,
    const float* __restrict__ pc, const u16* __restrict__ wpack, const float* __restrict__ v,
    const float* __restrict__ xw, float* __restrict__ part){
  __shared__ float SL[3*4820 + 8];            // H@0, P@4820, C@9640 (+pad for K-overflow reads)
  __shared__ float PS[2][16][18];
  __shared__ float PP[16];
  __shared__ float ML[2];
  int tid = threadIdx.x;
  int chunk = blockIdx.x, b = blockIdx.y;     // 64 chunks x 128 batches
  int rr0 = (b<<10) + chunk*16;
  const float* srcs[3] = { hs + (size_t)rr0*300, pht + (size_t)rr0*300, pc + (size_t)rr0*300 };
  // issue all DMA: 3 tensors x 19200B, 16B/lane, linear
  #pragma unroll
  for (int t=0;t<3;t++){
    const char* gsrc = (const char*)srcs[t];
    char* dstb = (char*)&SL[t*4820];
    #pragma unroll
    for (int r=0;r<5;r++){
      int off = r*4096 + tid*16;
      if (off < 19200) gl_lds16(gsrc + off, dstb + off);
    }
  }
  __syncthreads();                            // drains vmcnt for all DMA
  // MFMA score phase: waves 0,1 (tensor H/P), one 16x16 tile each; cvt f32->bf16 at use
  {
    int w = tid>>6, l = tid&63;
    if (w < 2){
      int c = l&15, g = l>>4;
      const float* SLt = &SL[w*4820];
      const u16* wbase = wpack + (size_t)w*5120;
      f32x4 acc = (f32x4){0.f,0.f,0.f,0.f};
      #pragma unroll
      for (int ks=0; ks<10; ks++){
        const float* ap = SLt + c*300 + ks*32 + g*8;
        f32x4 a0 = *(const f32x4*)ap;
        f32x4 a1 = *(const f32x4*)(ap+4);
        union{ u32 w4[4]; bf16x8 v8; } cv;
        cv.w4[0]=pk2(a0[0],a0[1]); cv.w4[1]=pk2(a0[2],a0[3]);
        cv.w4[2]=pk2(a1[0],a1[1]); cv.w4[3]=pk2(a1[2],a1[3]);
        bf16x8 bfr = *(const bf16x8*)(wbase + ((ks*4 + g)*16 + c)*8);
        acc = __builtin_amdgcn_mfma_f32_16x16x32_bf16(cv.v8, bfr, acc, 0, 0, 0);
      }
      #pragma unroll
      for (int r=0;r<4;r++) PS[w][g*4 + r][c] = acc[r];
    }
  }
  __syncthreads();
  // chunk softmax stats (lanes 0..15)
  if (tid < 16){
    float s = 0.f;
    #pragma unroll
    for (int k=0;k<10;k++)
      s += v[k]*tanhf(PS[0][tid][k] + PS[1][tid][k] + xw[b*16+k]);
    float m = s;
    #pragma unroll
    for (int off=1; off<16; off<<=1) m = fmaxf(m, __shfl_xor(m, off));
    float p = expf(s - m);
    float l = p;
    #pragma unroll
    for (int off=1; off<16; off<<=1) l += __shfl_xor(l, off);
    PP[tid] = p;
    if (tid==0){ ML[0]=m; ML[1]=l; }
  }
  __syncthreads();
  // weighted sums in f32 straight from LDS
  float* pp = part + ((size_t)b*64 + chunk)*608;
  if (tid < 150){
    int d = tid*2;
    const float* HLf = &SL[0];
    const float* CLf = &SL[9640];
    float h0=0,h1=0,c0=0,c1=0;
    #pragma unroll
    for (int t=0;t<16;t++){
      float p = PP[t];
      h0 = fmaf(p, HLf[t*300 + d],     h0);
      h1 = fmaf(p, HLf[t*300 + d + 1], h1);
      c0 = fmaf(p, CLf[t*300 + d],     c0);
      c1 = fmaf(p, CLf[t*300 + d + 1], c1);
    }
    *(float2*)(pp + 4 + d)   = float2{h0,h1};
    *(float2*)(pp + 308 + d) = float2{c0,c1};
  }
  if (tid==0){ pp[0]=ML[0]; pp[1]=ML[1]; }
}

// ---------------- combine 64 chunk-partials -> ct (f32) + cat600b (bf16: [ht|x]) ----------------
__global__ __launch_bounds__(192) void attn_reduce(const float* __restrict__ part,
    const float* __restrict__ x, float* __restrict__ ct, u16* __restrict__ catb){
  int b = blockIdx.x;
  int tid = threadIdx.x;
  const float* pb = part + (size_t)b*64*608;
  float M = -3.0e38f;
  #pragma unroll 8
  for (int j=0;j<64;j++) M = fmaxf(M, pb[j*608]);
  float L = 0.f;
  #pragma unroll 8
  for (int j=0;j<64;j++) L += pb[j*608+1]*expf(pb[j*608]-M);
  if (tid < 150){
    int d = tid*2;
    float a0=0,a1=0,b0=0,b1=0;
    #pragma unroll 8
    for (int j=0;j<64;j++){
      float w = expf(pb[j*608]-M);
      float2 hh = *(const float2*)(pb + j*608 + 4 + d);
      float2 cc = *(const float2*)(pb + j*608 + 308 + d);
      a0 = fmaf(w,hh.x,a0); a1 = fmaf(w,hh.y,a1);
      b0 = fmaf(w,cc.x,b0); b1 = fmaf(w,cc.y,b1);
    }
    float inv = 1.f/L;
    *(float2*)(ct + (size_t)b*300 + d) = float2{b0*inv, b1*inv};
    *(u32*)(catb + (size_t)b*608 + d)       = pk2(a0*inv, a1*inv);
    *(u32*)(catb + (size_t)b*608 + 300 + d) = pk2(x[(size_t)b*300 + d], x[(size_t)b*300 + d + 1]);
  }
}

// ---------------- MFMA dense layer: out[b][n] = bias[n] + sum_k inB[b,k]*Wb[n,k] ----------------
template<int KP, bool OUTBF>
__global__ __launch_bounds__(256) void gemm_mfma(int NW, int NB, int ldo,
    const u16* __restrict__ inB, const u16* __restrict__ Wb,
    const float* __restrict__ bias, void* __restrict__ outp){
  __shared__ float red[4][64][4];
  int w = threadIdx.x>>6, l = threadIdx.x&63;
  int c = l&15, g = l>>4;
  int n0 = blockIdx.x*16;
  int b0 = blockIdx.y*16;
  const u16* arow = Wb  + (size_t)(n0 + c)*KP + g*8;
  const u16* brow = inB + (size_t)(b0 + c)*KP + g*8;
  f32x4 acc = (f32x4){0.f,0.f,0.f,0.f};
  for (int ks = w; ks < KP/32; ks += 4){
    bf16x8 af = *(const bf16x8*)(arow + ks*32);
    bf16x8 bf = *(const bf16x8*)(brow + ks*32);
    acc = __builtin_amdgcn_mfma_f32_16x16x32_bf16(af, bf, acc, 0, 0, 0);
  }
  #pragma unroll
  for (int r=0;r<4;r++) red[w][l][r] = acc[r];
  __syncthreads();
  if (w==0){
    float s0 = red[0][l][0]+red[1][l][0]+red[2][l][0]+red[3][l][0];
    float s1 = red[0][l][1]+red[1][l][1]+red[2][l][1]+red[3][l][1];
    float s2 = red[0][l][2]+red[1][l][2]+red[2][l][2]+red[3][l][2];
    float s3 = red[0][l][3]+red[1][l][3]+red[2][l][3]+red[3][l][3];
    int b = b0 + c, nb = n0 + g*4;
    if (nb < NW){
      float4 bi;
      if (nb < NB) bi = *(const float4*)(bias + nb);
      else { bi.x=0; bi.y=0; bi.z=0; bi.w=0; }
      float o0=s0+bi.x, o1=s1+bi.y, o2=s2+bi.z, o3=s3+bi.w;
      if (OUTBF){
        ushort4 st; st.x=f2bf(o0); st.y=f2bf(o1); st.z=f2bf(o2); st.w=f2bf(o3);
        *(ushort4*)((u16*)outp + (size_t)b*ldo + nb) = st;
      } else {
        float4 st; st.x=o0; st.y=o1; st.z=o2; st.w=o3;
        *(float4*)((float*)outp + (size_t)b*ldo + nb) = st;
      }
    }
  }
}

// ---------------- scat (whx2 -> P0 bf16) + border rings of NHWC bufs ----------------
DEV void bzero(u16* buf, int j, int CH, int C){
  int c8 = j % CH; int rem = j / CH;
  int i = rem % 164, b = rem / 164;
  int y, x;
  if      (i < 42){ y = 0;        x = i; }
  else if (i < 84){ y = 41;       x = i-42; }
  else if (i < 124){ y = i-84+1;  x = 0; }
  else             { y = i-124+1; x = 41; }
  us8v z = {0,0,0,0,0,0,0,0};
  *(us8v*)(buf + ((size_t)b*1764 + y*42 + x)*C + c8*8) = z;
}
__global__ __launch_bounds__(256) void scat_border(const float* __restrict__ whx2, u16* __restrict__ p0,
    u16* __restrict__ A32, u16* __restrict__ B64, u16* __restrict__ C64){
  int id = blockIdx.x*256 + threadIdx.x;
  if (id < 204800){
    int b = id/1600, p = id%1600;
    int y = p/40, x = p%40;
    p0[(size_t)b*1764 + (y+1)*42 + (x+1)] = f2bf(whx2[id]);
  } else if (id < 288768){ bzero(A32, id-204800, 4, 32); }
  else if (id < 456704){ bzero(B64, id-288768, 8, 64); }
  else { bzero(C64, id-456704, 8, 64); }
}

// ---------------- LDS-tiled implicit-GEMM MFMA conv 3x3 + bias + relu + bn ----------------
template<int CI, int CO>
__global__ __launch_bounds__(256) void conv_tile(const u16* __restrict__ in, u16* __restrict__ out,
    const u16* __restrict__ wB, const float* __restrict__ par){
  constexpr int PCI  = CI + 8;
  constexpr int MF   = CO/16;
  constexpr int FPW  = MF;
  constexpr int KC   = CI/32;
  constexpr int KROW = CI*9;
  constexpr int CH8  = CI/8;
  __shared__ u16 TIN[100*PCI];
  int tile = blockIdx.x;
  int b = blockIdx.y;
  int y0 = (tile/5)*8, x0 = (tile%5)*8;
  const u16* inb = in + (size_t)b*1764*CI;
  for (int g = threadIdx.x; g < 100*CH8; g += 256){
    int pix = g/CH8, ch = g - pix*CH8;
    int r = pix/10, cc = pix - r*10;
    us8v vdat = *(const us8v*)(inb + ((size_t)(y0+r)*42 + (x0+cc))*CI + ch*8);
    *(us8v*)(&TIN[pix*PCI + ch*8]) = vdat;
  }
  __syncthreads();
  int w = threadIdx.x>>6, l = threadIdx.x&63;
  int c = l&15, kg = l>>4;
  int mg, f0;
  if (MF==4){ mg = w; f0 = 0; } else { mg = w&1; f0 = (w>>1)*2; }
  int pxb[FPW];
  #pragma unroll
  for (int fi=0; fi<FPW; fi++){
    int px = (f0+fi)*16 + c;
    int ty = px>>3, tx = px&7;
    pxb[fi] = (ty*10 + tx)*PCI + kg*8;
  }
  const u16* wrow = wB + (size_t)(mg*16 + c)*KROW;
  f32x4 acc[FPW];
  #pragma unroll
  for (int fi=0; fi<FPW; fi++) acc[fi] = (f32x4){0.f,0.f,0.f,0.f};
  #pragma unroll
  for (int dy=0;dy<3;dy++)
  #pragma unroll
  for (int dx=0;dx<3;dx++){
    int dydx = dy*3+dx;
    #pragma unroll
    for (int kc=0; kc<KC; kc++){
      bf16x8 af = *(const bf16x8*)(wrow + dydx*CI + kc*32 + kg*8);
      #pragma unroll
      for (int fi=0; fi<FPW; fi++){
        bf16x8 bf = *(const bf16x8*)(&TIN[pxb[fi] + (dy*10+dx)*PCI + kc*32]);
        acc[fi] = __builtin_amdgcn_mfma_f32_16x16x32_bf16(af, bf, acc[fi], 0, 0, 0);
      }
    }
  }
  u16* ob = out + (size_t)b*1764*CO;
  int co0 = mg*16 + kg*4;
  const float4 bia = *(const float4*)(par + co0);
  const float4 sc  = *(const float4*)(par + CO + co0);
  const float4 be  = *(const float4*)(par + 2*CO + co0);
  #pragma unroll
  for (int fi=0; fi<FPW; fi++){
    int px = (f0+fi)*16 + c;
    int y = y0 + (px>>3), x = x0 + (px&7);
    ushort4 s;
    s.x = f2bf(fmaxf(acc[fi][0]+bia.x,0.f)*sc.x + be.x);
    s.y = f2bf(fmaxf(acc[fi][1]+bia.y,0.f)*sc.y + be.y);
    s.z = f2bf(fmaxf(acc[fi][2]+bia.z,0.f)*sc.z + be.z);
    s.w = f2bf(fmaxf(acc[fi][3]+bia.w,0.f)*sc.w + be.w);
    *(ushort4*)(ob + (size_t)((y+1)*42 + (x+1))*CO + co0) = s;
  }
}

// ---------------- conv1 direct 1->32 ----------------
template<int CI, int CO, bool TT>
__global__ __launch_bounds__(256) void conv_main(const u16* __restrict__ in, u16* __restrict__ out,
    const float* __restrict__ w2, const float* __restrict__ par){
  int b = blockIdx.x;
  int wave = threadIdx.x >> 6;
  int lane = threadIdx.x & 63;
  int tile, co;
  if (TT){ tile = blockIdx.y*8 + wave*2 + (lane>>5); co = lane & 31; }
  else   { tile = blockIdx.y*4 + wave;               co = lane; }
  int y0 = (tile >> 3)*5, x0 = (tile & 7)*5;
  const u16* inb = in + (size_t)b*1764*CI;
  float acc[25];
  #pragma unroll
  for (int p=0;p<25;p++) acc[p]=0.f;
  for (int ci=0; ci<CI; ci++){
    float win[49];
    #pragma unroll
    for (int r=0;r<7;r++)
      #pragma unroll
      for (int c=0;c<7;c++)
        win[r*7+c] = bf2f(inb[ ((y0+r)*42 + (x0+c))*CI + ci ]);
    float wk[9];
    #pragma unroll
    for (int k=0;k<9;k++) wk[k] = w2[(ci*9+k)*CO + co];
    #pragma unroll
    for (int py=0;py<5;py++)
      #pragma unroll
      for (int px=0;px<5;px++){
        float s = acc[py*5+px];
        #pragma unroll
        for (int dy=0;dy<3;dy++)
          #pragma unroll
          for (int dx=0;dx<3;dx++)
            s = fmaf(wk[dy*3+dx], win[(py+dy)*7 + (px+dx)], s);
        acc[py*5+px] = s;
      }
  }
  float bia = par[co], sc = par[CO+co], be = par[2*CO+co];
  u16* outb = out + (size_t)b*1764*CO;
  #pragma unroll
  for (int py=0;py<5;py++)
    #pragma unroll
    for (int px=0;px<5;px++){
      float vv = fmaxf(acc[py*5+px] + bia, 0.f)*sc + be;
      outb[ ((y0+py+1)*42 + (x0+px+1))*CO + co ] = f2bf(vv);
    }
}

// ---------------- c6: 32 -> 1 channel ----------------
__global__ __launch_bounds__(256) void conv_c6(const u16* __restrict__ in, u16* __restrict__ y6,
    const float* __restrict__ w6, const float* __restrict__ par6){
  int id = blockIdx.x*256 + threadIdx.x;          // 128*1600
  int b = id/1600, p = id%1600;
  int y = p/40, x = p%40;
  const u16* inb = in + (size_t)b*1764*32;
  float acc = 0.f;
  #pragma unroll
  for (int dy=0;dy<3;dy++)
    #pragma unroll
    for (int dx=0;dx<3;dx++){
      const u16* q = inb + ((y+dy)*42 + (x+dx))*32;
      int k = dy*3+dx;
      #pragma unroll
      for (int g=0; g<4; g++){
        us8v vv8 = *(const us8v*)(q + g*8);
        #pragma unroll
        for (int j=0;j<8;j++)
          acc = fmaf(w6[(g*8+j)*9 + k], bf2f(vv8[j]), acc);
      }
    }
  float vv = fmaxf(acc + par6[0], 0.f)*par6[1] + par6[2];
  y6[(size_t)b*1764 + (y+1)*42 + (x+1)] = f2bf(vv);
}

// ---------------- pc: concat(pre, y6) 2 -> 1, no relu; writes bf16 for gemm3 ----------------
__global__ __launch_bounds__(256) void conv_pc(const u16* __restrict__ p0, const u16* __restrict__ y6,
    const float* __restrict__ pcw, const float* __restrict__ pcb,
    const float* __restrict__ pcg, const float* __restrict__ pcbe,
    u16* __restrict__ o16b){
  int id = blockIdx.x*256 + threadIdx.x;          // 128*1600
  int b = id/1600, p = id%1600;
  int y = p/40, x = p%40;
  float acc = 0.f;
  #pragma unroll
  for (int dy=0;dy<3;dy++)
    #pragma unroll
    for (int dx=0;dx<3;dx++){
      size_t o = (size_t)b*1764 + (y+dy)*42 + (x+dx);
      acc = fmaf(pcw[dy*3+dx],     bf2f(p0[o]), acc);
      acc = fmaf(pcw[9 + dy*3+dx], bf2f(y6[o]), acc);
    }
  float sc = pcg[0] * (1.0f/sqrtf(1.00001f));
  o16b[id] = f2bf((acc + pcb[0])*sc + pcbe[0]);
}

// ---------------- LSTM gating ----------------
__global__ __launch_bounds__(256) void gate_k(const float* __restrict__ whx3, const float* __restrict__ ct,
                                              float* __restrict__ outp){
  int id = blockIdx.x*256 + threadIdx.x;          // 128*300
  if (id >= 38400) return;
  int b = id/300, d = id%300;
  const float* r = whx3 + (size_t)b*1200;
  float ft = 1.f/(1.f+expf(-r[d]));
  float ot = 1.f/(1.f+expf(-r[300+d]));
  float it = 1.f/(1.f+expf(-r[600+d]));
  float ch = tanhf(r[900+d]);
  float c  = ft*ct[id] + it*ch;
  outp[id] = ot*tanhf(c);
}

extern "C" void kernel_launch(void* const* d_in, const int* in_sizes, int n_in,
                              void* d_out, int out_size, void* d_ws, size_t ws_size,
                              hipStream_t stream){
  const float* x    = (const float*)d_in[0];
  const float* hs   = (const float*)d_in[1];
  const float* pht  = (const float*)d_in[2];
  const float* pc   = (const float*)d_in[3];
  const float* W    = (const float*)d_in[4];
  const float* bb   = (const float*)d_in[5];
  const float* Wh   = (const float*)d_in[6];
  const float* Wx   = (const float*)d_in[7];
  const float* Wht  = (const float*)d_in[8];
  const float* v    = (const float*)d_in[9];
  const float* rbw  = (const float*)d_in[10];
  const float* rbb  = (const float*)d_in[11];
  const float* rpw  = (const float*)d_in[12];
  const float* rpb  = (const float*)d_in[13];
  const float *cw[6], *cb[6], *cg[6], *cbe[6];
  for (int i=0;i<6;i++){
    cw[i]=(const float*)d_in[14+4*i]; cb[i]=(const float*)d_in[15+4*i];
    cg[i]=(const float*)d_in[16+4*i]; cbe[i]=(const float*)d_in[17+4*i];
  }
  const float* pcw = (const float*)d_in[38];
  const float* pcb = (const float*)d_in[39];
  const float* pcg = (const float*)d_in[40];
  const float* pcbe= (const float*)d_in[41];

  char* ws = (char*)d_ws;
  float* xw    = (float*)(ws + OFF_XW);
  float* whx2  = (float*)(ws + OFF_WHX2);
  float* whx3  = (float*)(ws + OFF_WHX3);
  float* w21   = (float*)(ws + OFF_W21);
  u16*   wb2   = (u16*)  (ws + OFF_WB2);
  u16*   wb3   = (u16*)  (ws + OFF_WB3);
  u16*   wb4   = (u16*)  (ws + OFF_WB4);
  u16*   wb5   = (u16*)  (ws + OFF_WB5);
  float* w26   = (float*)(ws + OFF_W26);
  u16*   wpack = (u16*)  (ws + OFF_WPACK);
  u16*   wb1g  = (u16*)  (ws + OFF_WB1G);
  u16*   rbwb  = (u16*)  (ws + OFF_RBWB);
  u16*   rpwb  = (u16*)  (ws + OFF_RPWB);
  u16*   catb  = (u16*)  (ws + OFF_CAT);
  u16*   whx1b = (u16*)  (ws + OFF_WHX1B);
  u16*   o16b  = (u16*)  (ws + OFF_O16B);
  float* part  = (float*)(ws + OFF_PART);
  float* parb  = (float*)(ws + OFF_PAR);
  float* ct = (float*)(ws + OFF_CT);
  u16* A32 = (u16*)(ws + OFF_A32);
  u16* B64 = (u16*)(ws + OFF_B64);
  u16* C64 = (u16*)(ws + OFF_C64);
  u16* P0  = (u16*)(ws + OFF_P0);
  u16* Y6  = (u16*)(ws + OFF_Y6);

  RArgs ra;
  for (int i=0;i<6;i++){ ra.cw[i]=cw[i]; ra.cb[i]=cb[i]; ra.cg[i]=cg[i]; ra.cbe[i]=cbe[i]; }
  ra.Wh=Wh; ra.Wht=Wht; ra.Wg=W; ra.rbw=rbw; ra.rpw=rpw;
  ra.w21=w21; ra.w26=w26; ra.par=parb;
  ra.wb2=wb2; ra.wb3=wb3; ra.wb4=wb4; ra.wb5=wb5; ra.wpack=wpack;
  ra.Wb1=wb1g; ra.rbwb=rbwb; ra.rpwb=rpwb;

  // 0) init + repack
  zero_mega<<<165,256,0,stream>>>(P0, Y6, catb);
  mega_repack<<<2048,256,0,stream>>>(ra);

  // 1) fused attention (PART aliases C64; dead before conv3 writes it)
  xw_k<<<1280,64,0,stream>>>(x, Wx, xw);
  attn_fused<<<dim3(64,128),256,0,stream>>>(hs, pht, pc, wpack, v, xw, part);
  attn_reduce<<<128,192,0,stream>>>(part, x, ct, catb);

  // 2) dense layers (MFMA)
  gemm_mfma< 608,true ><<<dim3(76,8), 256,0,stream>>>(1216, 1200, 1216, catb,  wb1g, bb,  whx1b);
  gemm_mfma<1216,false><<<dim3(100,8),256,0,stream>>>(1600, 1600, 1600, whx1b, rbwb, rbb, whx2);
  scat_border<<<2440,256,0,stream>>>(whx2, P0, A32, B64, C64);

  // 3) conv block
  conv_main<1,32,true><<<dim3(128,8),256,0,stream>>>(P0, A32, w21, parb);
  conv_tile<32,64><<<dim3(25,128),256,0,stream>>>(A32, B64, wb2, parb + 192);
  conv_tile<64,64><<<dim3(25,128),256,0,stream>>>(B64, C64, wb3, parb + 384);
  conv_tile<64,64><<<dim3(25,128),256,0,stream>>>(C64, B64, wb4, parb + 576);
  conv_tile<64,32><<<dim3(25,128),256,0,stream>>>(B64, A32, wb5, parb + 768);
  conv_c6<<<800,256,0,stream>>>(A32, Y6, w26, parb + 960);
  conv_pc<<<800,256,0,stream>>>(P0, Y6, pcw, pcb, pcg, pcbe, o16b);

  // 4) final projection + gating
  gemm_mfma<1600,false><<<dim3(75,8),256,0,stream>>>(1200, 1200, 1200, o16b, rpwb, rpb, whx3);
  gate_k<<<150,256,0,stream>>>(whx3, ct, (float*)d_out);
}

// Round 13
// 352.879 us; speedup vs baseline: 1.0945x; 1.0945x over previous
//
#include <hip/hip_runtime.h>
#include <hip/hip_bf16.h>
#include <cstdint>
#include <cstddef>

typedef unsigned short u16;
typedef unsigned int u32;

#define DEV __device__ __forceinline__

DEV float bf2f(u16 u){ union{unsigned int i; float f;} c; c.i = ((unsigned)u)<<16; return c.f; }
DEV u16 f2bf(float f){ union{float f;unsigned int i;} c; c.f=f; unsigned int r = c.i + 0x7FFFu + ((c.i>>16)&1u); return (u16)(r>>16); }
DEV unsigned int pk2(float a, float b){
  __hip_bfloat162 t = __float22bfloat162_rn(float2{a,b});   // v_cvt_pk_bf16_f32
  union { __hip_bfloat162 h; unsigned int u; } cv; cv.h = t; return cv.u;
}

typedef __attribute__((ext_vector_type(8))) short bf16x8;
typedef __attribute__((ext_vector_type(4))) float f32x4;
typedef __attribute__((ext_vector_type(8))) unsigned short us8v;

// ---------------- workspace layout (bytes, all 16B aligned) ----------------
static constexpr size_t OFF_XW    = 0;                                   // [128][16] f32
static constexpr size_t OFF_WHX2  = 8192;                                // (spare)
static constexpr size_t OFF_WHX3  = OFF_WHX2 + (size_t)128*1600*4;       // [128][1200] f32
static constexpr size_t OFF_W21   = OFF_WHX3 + (size_t)128*1200*4;       // conv1 w [ci][k][co] f32
static constexpr size_t OFF_WB2   = OFF_W21  + (size_t)288*4;            // conv2 w bf16
static constexpr size_t OFF_WB3   = OFF_WB2  + (size_t)18432*2;
static constexpr size_t OFF_WB4   = OFF_WB3  + (size_t)36864*2;
static constexpr size_t OFF_WB5   = OFF_WB4  + (size_t)36864*2;
static constexpr size_t OFF_W26   = OFF_WB5  + (size_t)18432*2;          // conv6 w f32 [ci][k]
static constexpr size_t OFF_PAR   = OFF_W26  + (size_t)288*4;            // 6 x 768B
static constexpr size_t OFF_WPACK = OFF_PAR  + (size_t)6*768;            // score B-frags bf16
static constexpr size_t OFF_WB1G  = OFF_WPACK+ (size_t)20480*2;          // gemm1 W [1216][608] bf16
static constexpr size_t OFF_RBWB  = OFF_WB1G + (size_t)1216*608*2;       // gemm2 W [1600][1216] bf16
static constexpr size_t OFF_RPWB  = OFF_RBWB + (size_t)1600*1216*2;      // gemm3 W [1216][1600] bf16
static constexpr size_t OFF_CAT   = OFF_RPWB + (size_t)1216*1600*2;      // [128][608] bf16 (concat ht,x)
static constexpr size_t OFF_WHX1B = OFF_CAT  + (size_t)128*608*2;        // [128][1216] bf16
static constexpr size_t OFF_O16B  = OFF_WHX1B+ (size_t)128*1216*2;       // [128][1600] bf16
static constexpr size_t OFF_CT    = OFF_O16B + (size_t)128*1600*2;       // [128][300] f32
static constexpr size_t OFF_A32   = OFF_CT   + (size_t)128*300*4;        // [128][1764][32] bf16
static constexpr size_t OFF_B64   = OFF_A32  + (size_t)128*1764*32*2;    // [128][1764][64] bf16
static constexpr size_t OFF_C64   = OFF_B64  + (size_t)128*1764*64*2;    // [128][1764][64] bf16
static constexpr size_t OFF_P0    = OFF_C64  + (size_t)128*1764*64*2;    // [128][1764] bf16
static constexpr size_t OFF_Y6    = OFF_P0   + (size_t)128*1764*2;       // [128][1764] bf16
static constexpr size_t OFF_PARTX = OFF_Y6   + (size_t)128*1764*2;       // [128][32][608] f32 partials (own space)
static constexpr size_t OFF_END   = OFF_PARTX+ (size_t)128*32*608*4;

// ---------------- helpers for zero/border work ----------------
DEV void ring0(u16* buf, int j){
  int b = j/164, i = j%164;
  int y, x;
  if      (i < 42){ y = 0;        x = i; }
  else if (i < 84){ y = 41;       x = i-42; }
  else if (i < 124){ y = i-84+1;  x = 0; }
  else             { y = i-124+1; x = 41; }
  buf[(size_t)b*1764 + y*42 + x] = 0;
}
DEV void bzero(u16* buf, int j, int CH, int C){
  int c8 = j % CH; int rem = j / CH;
  int i = rem % 164, b = rem / 164;
  int y, x;
  if      (i < 42){ y = 0;        x = i; }
  else if (i < 84){ y = 41;       x = i-42; }
  else if (i < 124){ y = i-84+1;  x = 0; }
  else             { y = i-124+1; x = 41; }
  us8v z = {0,0,0,0,0,0,0,0};
  *(us8v*)(buf + ((size_t)b*1764 + y*42 + x)*C + c8*8) = z;
}
DEV void cvW(const float* w, u16* dst, size_t j, int CI){
  int ci = j % CI; size_t rem = j / CI; int dydx = rem % 9; int co = rem / 9;
  dst[j] = f2bf(w[((size_t)co*CI + ci)*9 + dydx]);
}

// ---------------- prep: wpack build + xw dot-products (one small launch) ----------------
__global__ __launch_bounds__(256) void prep_k(const float* __restrict__ Wh, const float* __restrict__ Wht,
    const float* __restrict__ x, const float* __restrict__ Wx,
    u16* __restrict__ wp, float* __restrict__ xw){
  int bid = blockIdx.x, tid = threadIdx.x;
  if (bid < 80){
    int j = bid*256 + tid;                    // 20480 exact
    int jj = j&7, col=(j>>3)&15, kg=(j>>7)&3, rest=j>>9;
    int ks = rest%10, tz = rest/10;
    int k = ks*32 + kg*8 + jj;
    const float* src = tz ? Wht : Wh;
    wp[j] = f2bf((col<10 && k<300)? src[col*300+k] : 0.f);
  } else {
    int gw = (bid-80)*4 + (tid>>6);           // 1280 waves: (b,k)
    int lane = tid & 63;
    int b = gw/10, k = gw%10;
    float a = 0.f;
    for (int d = lane; d < 300; d += 64)
      a = fmaf(x[b*300+d], Wx[k*300+d], a);
    #pragma unroll
    for (int off=1; off<64; off<<=1) a += __shfl_xor(a, off);
    if (lane==0) xw[b*16+k] = a;
  }
}

// ---------------- hetero mega-kernel: [attn 4096 | zero/border 1805 | repack 512] ----------------
struct MArgs {
  const float *hs, *pht, *pc, *v, *xw;
  const u16* wpack;
  float* part;
  const float* cw0; const float* cw1; const float* cw2; const float* cw3; const float* cw4; const float* cw5;
  const float* cb[6]; const float* cg[6]; const float* cbe[6];
  const float* Wg; const float* rbw; const float* rpw;
  float* w21; float* w26; float* par;
  u16 *wb2, *wb3, *wb4, *wb5, *Wb1, *rbwb, *rpwb;
  u16 *p0, *y6, *catb, *A32, *B64, *C64;
};
__global__ __launch_bounds__(256,3) void attn_mega(MArgs a){
  int bid = blockIdx.x;
  int tid = threadIdx.x;
  if (bid < 4096){
    // ---- r9-exact fused attention: 32-row chunk ----
    __shared__ u16 HL[32][328];
    __shared__ u16 PL[32][328];
    __shared__ float PS[2][32][18];
    __shared__ float PP[32];
    __shared__ float ML[2];
    int chunk = bid & 31, b = bid >> 5;
    int rr0 = (b<<10) + chunk*32;
    const float* hsrc = a.hs  + (size_t)rr0*300;
    const float* psrc = a.pht + (size_t)rr0*300;
    const float* csrc = a.pc  + (size_t)rr0*300;
    float4 creg[10];
    #pragma unroll
    for (int rnd=0; rnd<10; rnd++){
      int idx = rnd*256 + tid;
      if (idx < 2400) creg[rnd] = *(const float4*)(csrc + idx*4);
    }
    #pragma unroll
    for (int rnd=0; rnd<10; rnd++){
      int idx = rnd*256 + tid;
      if (idx < 2400){
        float4 qh = *(const float4*)(hsrc + idx*4);
        float4 qp = *(const float4*)(psrc + idx*4);
        int row = idx/75, colp = (idx - row*75)*4;
        uint2 pvh; pvh.x = pk2(qh.x,qh.y); pvh.y = pk2(qh.z,qh.w);
        uint2 pvp; pvp.x = pk2(qp.x,qp.y); pvp.y = pk2(qp.z,qp.w);
        *(uint2*)(&HL[row][colp]) = pvh;
        *(uint2*)(&PL[row][colp]) = pvp;
      }
    }
    #pragma unroll
    for (int j=0;j<2;j++){
      int idx = j*256 + tid;
      if (idx < 448){
        int row = idx/14, cc = 300 + (idx - row*14)*2;
        *(u32*)(&HL[row][cc]) = 0u;
        *(u32*)(&PL[row][cc]) = 0u;
      }
    }
    __syncthreads();
    {
      int w = tid>>6, l = tid&63;
      int c = l&15, g = l>>4;
      int tz = w>>1, rf = w&1;
      const u16 (*SL)[328] = tz ? PL : HL;
      const u16* wbase = a.wpack + (size_t)tz*5120;
      f32x4 acc = (f32x4){0.f,0.f,0.f,0.f};
      #pragma unroll
      for (int ks=0; ks<10; ks++){
        bf16x8 af  = *(const bf16x8*)(&SL[rf*16 + c][ks*32 + g*8]);
        bf16x8 bfr = *(const bf16x8*)(wbase + ((ks*4 + g)*16 + c)*8);
        acc = __builtin_amdgcn_mfma_f32_16x16x32_bf16(af, bfr, acc, 0, 0, 0);
      }
      #pragma unroll
      for (int r=0;r<4;r++) PS[tz][rf*16 + g*4 + r][c] = acc[r];
    }
    __syncthreads();
    #pragma unroll
    for (int rnd=0; rnd<10; rnd++){
      int idx = rnd*256 + tid;
      if (idx < 2400){
        int row = idx/75, colp = (idx - row*75)*4;
        uint2 pv; pv.x = pk2(creg[rnd].x, creg[rnd].y); pv.y = pk2(creg[rnd].z, creg[rnd].w);
        *(uint2*)(&PL[row][colp]) = pv;
      }
    }
    if (tid < 32){
      float s = 0.f;
      #pragma unroll
      for (int k=0;k<10;k++)
        s += a.v[k]*tanhf(PS[0][tid][k] + PS[1][tid][k] + a.xw[b*16+k]);
      float m = s;
      #pragma unroll
      for (int off=1; off<32; off<<=1) m = fmaxf(m, __shfl_xor(m, off));
      float p = expf(s - m);
      float l = p;
      #pragma unroll
      for (int off=1; off<32; off<<=1) l += __shfl_xor(l, off);
      PP[tid] = p;
      if (tid==0){ ML[0]=m; ML[1]=l; }
    }
    __syncthreads();
    float* pp = a.part + ((size_t)b*32 + chunk)*608;
    if (tid < 150){
      int d = tid*2;
      float h0=0,h1=0,c0=0,c1=0;
      #pragma unroll
      for (int t=0;t<32;t++){
        float p = PP[t];
        u32 hw = *(const u32*)(&HL[t][d]);
        u32 cw = *(const u32*)(&PL[t][d]);
        h0 = fmaf(p, bf2f((u16)hw),       h0);
        h1 = fmaf(p, bf2f((u16)(hw>>16)), h1);
        c0 = fmaf(p, bf2f((u16)cw),       c0);
        c1 = fmaf(p, bf2f((u16)(cw>>16)), c1);
      }
      *(float2*)(pp + 4 + d)   = float2{h0,h1};
      *(float2*)(pp + 308 + d) = float2{c0,c1};
    }
    if (tid==0){ pp[0]=ML[0]; pp[1]=ML[1]; }
  } else if (bid < 5901){
    // ---- zero rings / borders / cat pad ----
    int zid = (bid-4096)*256 + tid;
    if (zid < 20992) ring0(a.p0, zid);
    else if (zid < 41984) ring0(a.y6, zid-20992);
    else if (zid < 42112){
      int b = zid - 41984;
      us8v z = {0,0,0,0,0,0,0,0};
      *(us8v*)(a.catb + (size_t)b*608 + 600) = z;
    }
    else if (zid < 126080){ bzero(a.A32, zid-42112, 4, 32); }
    else if (zid < 294016){ bzero(a.B64, zid-126080, 8, 64); }
    else if (zid < 461952){ bzero(a.C64, zid-294016, 8, 64); }
  } else {
    // ---- weight repack (co-executes with attention) ----
    const float isc = 1.0f/sqrtf(1.00001f);
    const float* cwA[6] = {a.cw0,a.cw1,a.cw2,a.cw3,a.cw4,a.cw5};
    for (size_t id = (size_t)(bid-5901)*256 + tid; id < 4742467ull; id += (size_t)512*256){
      if (id < 288){
        int co = id % 32; size_t rem = id / 32; int k = rem % 9;
        a.w21[id] = cwA[0][co*9 + k];
      } else if (id < 18720){ cvW(cwA[1], a.wb2, id-288, 32); }
      else if (id < 55584){ cvW(cwA[2], a.wb3, id-18720, 64); }
      else if (id < 92448){ cvW(cwA[3], a.wb4, id-55584, 64); }
      else if (id < 110880){ cvW(cwA[4], a.wb5, id-92448, 64); }
      else if (id < 111168){
        size_t j = id - 110880;
        a.w26[j] = cwA[5][j];
      } else if (id < 850496){
        size_t j = id - 111168; int k = (int)(j % 608); int n = (int)(j / 608);
        a.Wb1[j] = f2bf((n<1200 && k<600)? a.Wg[(size_t)n*600+k] : 0.f);
      } else if (id < 2796096){
        size_t j = id - 850496; int k = (int)(j % 1216); int n = (int)(j / 1216);
        a.rbwb[j] = f2bf((k<1200)? a.rbw[(size_t)n*1200+k] : 0.f);
      } else if (id < 4741696){
        size_t j = id - 2796096; int k = (int)(j % 1600); int n = (int)(j / 1600);
        a.rpwb[j] = f2bf((n<1200)? a.rpw[(size_t)n*1600+k] : 0.f);
      } else {
        size_t j = id - 4741696;             // 771 par entries
        int ci, CO; size_t base;
        if (j < 96){ ci=0; CO=32; base=0; }
        else if (j < 288){ ci=1; CO=64; base=96; }
        else if (j < 480){ ci=2; CO=64; base=288; }
        else if (j < 672){ ci=3; CO=64; base=480; }
        else if (j < 768){ ci=4; CO=32; base=672; }
        else { ci=5; CO=1; base=768; }
        size_t jj = j - base; int t = (int)(jj / CO); int c = (int)(jj % CO);
        float* p = a.par + (size_t)ci*192;
        p[t*CO + c] = (t==0)? a.cb[ci][c] : (t==1)? a.cg[ci][c]*isc : a.cbe[ci][c];
      }
    }
  }
}

// ---------------- combine 32 chunk-partials -> ct (f32) + cat600b (bf16: [ht|x]) ----------------
__global__ __launch_bounds__(192) void attn_reduce(const float* __restrict__ part,
    const float* __restrict__ x, float* __restrict__ ct, u16* __restrict__ catb){
  int b = blockIdx.x;
  int tid = threadIdx.x;
  const float* pb = part + (size_t)b*32*608;
  float M = -3.0e38f;
  #pragma unroll
  for (int j=0;j<32;j++) M = fmaxf(M, pb[j*608]);
  float L = 0.f;
  #pragma unroll
  for (int j=0;j<32;j++) L += pb[j*608+1]*expf(pb[j*608]-M);
  if (tid < 150){
    int d = tid*2;
    float a0=0,a1=0,b0=0,b1=0;
    #pragma unroll
    for (int j=0;j<32;j++){
      float w = expf(pb[j*608]-M);
      float2 hh = *(const float2*)(pb + j*608 + 4 + d);
      float2 cc = *(const float2*)(pb + j*608 + 308 + d);
      a0 = fmaf(w,hh.x,a0); a1 = fmaf(w,hh.y,a1);
      b0 = fmaf(w,cc.x,b0); b1 = fmaf(w,cc.y,b1);
    }
    float inv = 1.f/L;
    *(float2*)(ct + (size_t)b*300 + d) = float2{b0*inv, b1*inv};
    *(u32*)(catb + (size_t)b*608 + d)       = pk2(a0*inv, a1*inv);
    *(u32*)(catb + (size_t)b*608 + 300 + d) = pk2(x[(size_t)b*300 + d], x[(size_t)b*300 + d + 1]);
  }
}

// ---------------- MFMA dense layer: out[b][n] = bias[n] + sum_k inB[b,k]*Wb[n,k] ----------------
// OMODE: 0 = f32 linear, 1 = bf16 linear, 2 = bf16 scatter into padded P0
template<int KP, int OMODE>
__global__ __launch_bounds__(256) void gemm_mfma(int NW, int NB, int ldo,
    const u16* __restrict__ inB, const u16* __restrict__ Wb,
    const float* __restrict__ bias, void* __restrict__ outp){
  __shared__ float red[4][64][4];
  int w = threadIdx.x>>6, l = threadIdx.x&63;
  int c = l&15, g = l>>4;
  int n0 = blockIdx.x*16;
  int b0 = blockIdx.y*16;
  const u16* arow = Wb  + (size_t)(n0 + c)*KP + g*8;
  const u16* brow = inB + (size_t)(b0 + c)*KP + g*8;
  f32x4 acc = (f32x4){0.f,0.f,0.f,0.f};
  for (int ks = w; ks < KP/32; ks += 4){
    bf16x8 af = *(const bf16x8*)(arow + ks*32);
    bf16x8 bf = *(const bf16x8*)(brow + ks*32);
    acc = __builtin_amdgcn_mfma_f32_16x16x32_bf16(af, bf, acc, 0, 0, 0);
  }
  #pragma unroll
  for (int r=0;r<4;r++) red[w][l][r] = acc[r];
  __syncthreads();
  if (w==0){
    float s0 = red[0][l][0]+red[1][l][0]+red[2][l][0]+red[3][l][0];
    float s1 = red[0][l][1]+red[1][l][1]+red[2][l][1]+red[3][l][1];
    float s2 = red[0][l][2]+red[1][l][2]+red[2][l][2]+red[3][l][2];
    float s3 = red[0][l][3]+red[1][l][3]+red[2][l][3]+red[3][l][3];
    int b = b0 + c, nb = n0 + g*4;
    if (nb < NW){
      float4 bi;
      if (nb < NB) bi = *(const float4*)(bias + nb);
      else { bi.x=0; bi.y=0; bi.z=0; bi.w=0; }
      float o0=s0+bi.x, o1=s1+bi.y, o2=s2+bi.z, o3=s3+bi.w;
      if (OMODE==2){
        int row = nb/40, col = nb%40;         // 4-run never crosses a row (40%4==0)
        u16* pp0 = (u16*)outp + (size_t)b*1764 + (row+1)*42 + (col+1);
        pp0[0]=f2bf(o0); pp0[1]=f2bf(o1); pp0[2]=f2bf(o2); pp0[3]=f2bf(o3);
      } else if (OMODE==1){
        ushort4 st; st.x=f2bf(o0); st.y=f2bf(o1); st.z=f2bf(o2); st.w=f2bf(o3);
        *(ushort4*)((u16*)outp + (size_t)b*ldo + nb) = st;
      } else {
        float4 st; st.x=o0; st.y=o1; st.z=o2; st.w=o3;
        *(float4*)((float*)outp + (size_t)b*ldo + nb) = st;
      }
    }
  }
}

// ---------------- LDS-tiled implicit-GEMM MFMA conv 3x3 + bias + relu + bn ----------------
template<int CI, int CO>
__global__ __launch_bounds__(256) void conv_tile(const u16* __restrict__ in, u16* __restrict__ out,
    const u16* __restrict__ wB, const float* __restrict__ par){
  constexpr int PCI  = CI + 8;
  constexpr int MF   = CO/16;
  constexpr int FPW  = MF;
  constexpr int KC   = CI/32;
  constexpr int KROW = CI*9;
  constexpr int CH8  = CI/8;
  __shared__ u16 TIN[100*PCI];
  int tile = blockIdx.x;
  int b = blockIdx.y;
  int y0 = (tile/5)*8, x0 = (tile%5)*8;
  const u16* inb = in + (size_t)b*1764*CI;
  for (int g = threadIdx.x; g < 100*CH8; g += 256){
    int pix = g/CH8, ch = g - pix*CH8;
    int r = pix/10, cc = pix - r*10;
    us8v vdat = *(const us8v*)(inb + ((size_t)(y0+r)*42 + (x0+cc))*CI + ch*8);
    *(us8v*)(&TIN[pix*PCI + ch*8]) = vdat;
  }
  __syncthreads();
  int w = threadIdx.x>>6, l = threadIdx.x&63;
  int c = l&15, kg = l>>4;
  int mg, f0;
  if (MF==4){ mg = w; f0 = 0; } else { mg = w&1; f0 = (w>>1)*2; }
  int pxb[FPW];
  #pragma unroll
  for (int fi=0; fi<FPW; fi++){
    int px = (f0+fi)*16 + c;
    int ty = px>>3, tx = px&7;
    pxb[fi] = (ty*10 + tx)*PCI + kg*8;
  }
  const u16* wrow = wB + (size_t)(mg*16 + c)*KROW;
  f32x4 acc[FPW];
  #pragma unroll
  for (int fi=0; fi<FPW; fi++) acc[fi] = (f32x4){0.f,0.f,0.f,0.f};
  #pragma unroll
  for (int dy=0;dy<3;dy++)
  #pragma unroll
  for (int dx=0;dx<3;dx++){
    int dydx = dy*3+dx;
    #pragma unroll
    for (int kc=0; kc<KC; kc++){
      bf16x8 af = *(const bf16x8*)(wrow + dydx*CI + kc*32 + kg*8);
      #pragma unroll
      for (int fi=0; fi<FPW; fi++){
        bf16x8 bf = *(const bf16x8*)(&TIN[pxb[fi] + (dy*10+dx)*PCI + kc*32]);
        acc[fi] = __builtin_amdgcn_mfma_f32_16x16x32_bf16(af, bf, acc[fi], 0, 0, 0);
      }
    }
  }
  u16* ob = out + (size_t)b*1764*CO;
  int co0 = mg*16 + kg*4;
  const float4 bia = *(const float4*)(par + co0);
  const float4 sc  = *(const float4*)(par + CO + co0);
  const float4 be  = *(const float4*)(par + 2*CO + co0);
  #pragma unroll
  for (int fi=0; fi<FPW; fi++){
    int px = (f0+fi)*16 + c;
    int y = y0 + (px>>3), x = x0 + (px&7);
    ushort4 s;
    s.x = f2bf(fmaxf(acc[fi][0]+bia.x,0.f)*sc.x + be.x);
    s.y = f2bf(fmaxf(acc[fi][1]+bia.y,0.f)*sc.y + be.y);
    s.z = f2bf(fmaxf(acc[fi][2]+bia.z,0.f)*sc.z + be.z);
    s.w = f2bf(fmaxf(acc[fi][3]+bia.w,0.f)*sc.w + be.w);
    *(ushort4*)(ob + (size_t)((y+1)*42 + (x+1))*CO + co0) = s;
  }
}

// ---------------- conv1 direct 1->32 ----------------
template<int CI, int CO, bool TT>
__global__ __launch_bounds__(256) void conv_main(const u16* __restrict__ in, u16* __restrict__ out,
    const float* __restrict__ w2, const float* __restrict__ par){
  int b = blockIdx.x;
  int wave = threadIdx.x >> 6;
  int lane = threadIdx.x & 63;
  int tile, co;
  if (TT){ tile = blockIdx.y*8 + wave*2 + (lane>>5); co = lane & 31; }
  else   { tile = blockIdx.y*4 + wave;               co = lane; }
  int y0 = (tile >> 3)*5, x0 = (tile & 7)*5;
  const u16* inb = in + (size_t)b*1764*CI;
  float acc[25];
  #pragma unroll
  for (int p=0;p<25;p++) acc[p]=0.f;
  for (int ci=0; ci<CI; ci++){
    float win[49];
    #pragma unroll
    for (int r=0;r<7;r++)
      #pragma unroll
      for (int c=0;c<7;c++)
        win[r*7+c] = bf2f(inb[ ((y0+r)*42 + (x0+c))*CI + ci ]);
    float wk[9];
    #pragma unroll
    for (int k=0;k<9;k++) wk[k] = w2[(ci*9+k)*CO + co];
    #pragma unroll
    for (int py=0;py<5;py++)
      #pragma unroll
      for (int px=0;px<5;px++){
        float s = acc[py*5+px];
        #pragma unroll
        for (int dy=0;dy<3;dy++)
          #pragma unroll
          for (int dx=0;dx<3;dx++)
            s = fmaf(wk[dy*3+dx], win[(py+dy)*7 + (px+dx)], s);
        acc[py*5+px] = s;
      }
  }
  float bia = par[co], sc = par[CO+co], be = par[2*CO+co];
  u16* outb = out + (size_t)b*1764*CO;
  #pragma unroll
  for (int py=0;py<5;py++)
    #pragma unroll
    for (int px=0;px<5;px++){
      float vv = fmaxf(acc[py*5+px] + bia, 0.f)*sc + be;
      outb[ ((y0+py+1)*42 + (x0+px+1))*CO + co ] = f2bf(vv);
    }
}

// ---------------- c6: 32 -> 1 channel ----------------
__global__ __launch_bounds__(256) void conv_c6(const u16* __restrict__ in, u16* __restrict__ y6,
    const float* __restrict__ w6, const float* __restrict__ par6){
  int id = blockIdx.x*256 + threadIdx.x;          // 128*1600
  int b = id/1600, p = id%1600;
  int y = p/40, x = p%40;
  const u16* inb = in + (size_t)b*1764*32;
  float acc = 0.f;
  #pragma unroll
  for (int dy=0;dy<3;dy++)
    #pragma unroll
    for (int dx=0;dx<3;dx++){
      const u16* q = inb + ((y+dy)*42 + (x+dx))*32;
      int k = dy*3+dx;
      #pragma unroll
      for (int g=0; g<4; g++){
        us8v vv8 = *(const us8v*)(q + g*8);
        #pragma unroll
        for (int j=0;j<8;j++)
          acc = fmaf(w6[(g*8+j)*9 + k], bf2f(vv8[j]), acc);
      }
    }
  float vv = fmaxf(acc + par6[0], 0.f)*par6[1] + par6[2];
  y6[(size_t)b*1764 + (y+1)*42 + (x+1)] = f2bf(vv);
}

// ---------------- pc: concat(pre, y6) 2 -> 1, no relu; writes bf16 for gemm3 ----------------
__global__ __launch_bounds__(256) void conv_pc(const u16* __restrict__ p0, const u16* __restrict__ y6,
    const float* __restrict__ pcw, const float* __restrict__ pcb,
    const float* __restrict__ pcg, const float* __restrict__ pcbe,
    u16* __restrict__ o16b){
  int id = blockIdx.x*256 + threadIdx.x;          // 128*1600
  int b = id/1600, p = id%1600;
  int y = p/40, x = p%40;
  float acc = 0.f;
  #pragma unroll
  for (int dy=0;dy<3;dy++)
    #pragma unroll
    for (int dx=0;dx<3;dx++){
      size_t o = (size_t)b*1764 + (y+dy)*42 + (x+dx);
      acc = fmaf(pcw[dy*3+dx],     bf2f(p0[o]), acc);
      acc = fmaf(pcw[9 + dy*3+dx], bf2f(y6[o]), acc);
    }
  float sc = pcg[0] * (1.0f/sqrtf(1.00001f));
  o16b[id] = f2bf((acc + pcb[0])*sc + pcbe[0]);
}

// ---------------- LSTM gating ----------------
__global__ __launch_bounds__(256) void gate_k(const float* __restrict__ whx3, const float* __restrict__ ct,
                                              float* __restrict__ outp){
  int id = blockIdx.x*256 + threadIdx.x;          // 128*300
  if (id >= 38400) return;
  int b = id/300, d = id%300;
  const float* r = whx3 + (size_t)b*1200;
  float ft = 1.f/(1.f+expf(-r[d]));
  float ot = 1.f/(1.f+expf(-r[300+d]));
  float it = 1.f/(1.f+expf(-r[600+d]));
  float ch = tanhf(r[900+d]);
  float c  = ft*ct[id] + it*ch;
  outp[id] = ot*tanhf(c);
}

extern "C" void kernel_launch(void* const* d_in, const int* in_sizes, int n_in,
                              void* d_out, int out_size, void* d_ws, size_t ws_size,
                              hipStream_t stream){
  const float* x    = (const float*)d_in[0];
  const float* hs   = (const float*)d_in[1];
  const float* pht  = (const float*)d_in[2];
  const float* pc   = (const float*)d_in[3];
  const float* W    = (const float*)d_in[4];
  const float* bb   = (const float*)d_in[5];
  const float* Wh   = (const float*)d_in[6];
  const float* Wx   = (const float*)d_in[7];
  const float* Wht  = (const float*)d_in[8];
  const float* v    = (const float*)d_in[9];
  const float* rbw  = (const float*)d_in[10];
  const float* rbb  = (const float*)d_in[11];
  const float* rpw  = (const float*)d_in[12];
  const float* rpb  = (const float*)d_in[13];
  const float *cw[6], *cb[6], *cg[6], *cbe[6];
  for (int i=0;i<6;i++){
    cw[i]=(const float*)d_in[14+4*i]; cb[i]=(const float*)d_in[15+4*i];
    cg[i]=(const float*)d_in[16+4*i]; cbe[i]=(const float*)d_in[17+4*i];
  }
  const float* pcw = (const float*)d_in[38];
  const float* pcb = (const float*)d_in[39];
  const float* pcg = (const float*)d_in[40];
  const float* pcbe= (const float*)d_in[41];

  char* ws = (char*)d_ws;
  float* xw    = (float*)(ws + OFF_XW);
  float* whx3  = (float*)(ws + OFF_WHX3);
  float* w21   = (float*)(ws + OFF_W21);
  u16*   wb2   = (u16*)  (ws + OFF_WB2);
  u16*   wb3   = (u16*)  (ws + OFF_WB3);
  u16*   wb4   = (u16*)  (ws + OFF_WB4);
  u16*   wb5   = (u16*)  (ws + OFF_WB5);
  float* w26   = (float*)(ws + OFF_W26);
  u16*   wpack = (u16*)  (ws + OFF_WPACK);
  u16*   wb1g  = (u16*)  (ws + OFF_WB1G);
  u16*   rbwb  = (u16*)  (ws + OFF_RBWB);
  u16*   rpwb  = (u16*)  (ws + OFF_RPWB);
  u16*   catb  = (u16*)  (ws + OFF_CAT);
  u16*   whx1b = (u16*)  (ws + OFF_WHX1B);
  u16*   o16b  = (u16*)  (ws + OFF_O16B);
  float* part  = (float*)(ws + OFF_PARTX);
  float* parb  = (float*)(ws + OFF_PAR);
  float* ct = (float*)(ws + OFF_CT);
  u16* A32 = (u16*)(ws + OFF_A32);
  u16* B64 = (u16*)(ws + OFF_B64);
  u16* C64 = (u16*)(ws + OFF_C64);
  u16* P0  = (u16*)(ws + OFF_P0);
  u16* Y6  = (u16*)(ws + OFF_Y6);

  MArgs ma;
  ma.hs=hs; ma.pht=pht; ma.pc=pc; ma.v=v; ma.xw=xw; ma.wpack=wpack; ma.part=part;
  ma.cw0=cw[0]; ma.cw1=cw[1]; ma.cw2=cw[2]; ma.cw3=cw[3]; ma.cw4=cw[4]; ma.cw5=cw[5];
  for (int i=0;i<6;i++){ ma.cb[i]=cb[i]; ma.cg[i]=cg[i]; ma.cbe[i]=cbe[i]; }
  ma.Wg=W; ma.rbw=rbw; ma.rpw=rpw;
  ma.w21=w21; ma.w26=w26; ma.par=parb;
  ma.wb2=wb2; ma.wb3=wb3; ma.wb4=wb4; ma.wb5=wb5;
  ma.Wb1=wb1g; ma.rbwb=rbwb; ma.rpwb=rpwb;
  ma.p0=P0; ma.y6=Y6; ma.catb=catb; ma.A32=A32; ma.B64=B64; ma.C64=C64;

  // 1) prep (wpack + xw), then hetero mega: attention || zero/borders || repack
  prep_k<<<400,256,0,stream>>>(Wh, Wht, x, Wx, wpack, xw);
  attn_mega<<<6413,256,0,stream>>>(ma);
  attn_reduce<<<128,192,0,stream>>>(part, x, ct, catb);

  // 2) dense layers (MFMA); gemm2 scatters bf16 directly into padded P0
  gemm_mfma< 608,1><<<dim3(76,8), 256,0,stream>>>(1216, 1200, 1216, catb,  wb1g, bb,  whx1b);
  gemm_mfma<1216,2><<<dim3(100,8),256,0,stream>>>(1600, 1600, 0,    whx1b, rbwb, rbb, P0);

  // 3) conv block
  conv_main<1,32,true><<<dim3(128,8),256,0,stream>>>(P0, A32, w21, parb);
  conv_tile<32,64><<<dim3(25,128),256,0,stream>>>(A32, B64, wb2, parb + 192);
  conv_tile<64,64><<<dim3(25,128),256,0,stream>>>(B64, C64, wb3, parb + 384);
  conv_tile<64,64><<<dim3(25,128),256,0,stream>>>(C64, B64, wb4, parb + 576);
  conv_tile<64,32><<<dim3(25,128),256,0,stream>>>(B64, A32, wb5, parb + 768);
  conv_c6<<<800,256,0,stream>>>(A32, Y6, w26, parb + 960);
  conv_pc<<<800,256,0,stream>>>(P0, Y6, pcw, pcb, pcg, pcbe, o16b);

  // 4) final projection + gating
  gemm_mfma<1600,0><<<dim3(75,8),256,0,stream>>>(1200, 1200, 1200, o16b, rpwb, rpb, whx3);
  gate_k<<<150,256,0,stream>>>(whx3, ct, (float*)d_out);
}